// Round 7
// baseline (145.714 us; speedup 1.0000x reference)
//
#include <hip/hip_runtime.h>
#include <math.h>

#define N_TOK 2048          // tokens per modality (64*32)
#define NMOD  3
#define NTOT  6144          // N_TOK * NMOD
#define D     256
#define INV_TAU 10.0f

#define BM 128              // output tile (rows == cols)
#define BK 32               // k-step (32 bf16 = 64 B rows)
#define NBLK (NTOT / BM)    // 48
#define KSTEPS (D / BK)     // 8

typedef float  f32x4  __attribute__((ext_vector_type(4)));
typedef short  bf16x8 __attribute__((ext_vector_type(8)));

// ------------------------------------------------------------- helpers
__device__ __forceinline__ unsigned short f2bf(float x) {
    unsigned int u = __float_as_uint(x);
    unsigned int r = (u + 0x7fffu + ((u >> 16) & 1u)) >> 16;   // RNE
    return (unsigned short)r;
}

__device__ __forceinline__ void gload16(const void* g, void* s) {
    __builtin_amdgcn_global_load_lds(
        (const __attribute__((address_space(1))) void*)g,
        (__attribute__((address_space(3))) void*)s, 16, 0, 0);
}

// ------------------------------------------------------------- normalize + bf16
__global__ void norm_kernel(const float* __restrict__ a,
                            const float* __restrict__ b,
                            const float* __restrict__ c,
                            unsigned short* __restrict__ H) {
    int row = blockIdx.x;
    const float* src;
    if (row < N_TOK)            src = a + (size_t)row * D;
    else if (row < 2 * N_TOK)   src = b + (size_t)(row - N_TOK) * D;
    else                        src = c + (size_t)(row - 2 * N_TOK) * D;

    int t = threadIdx.x;                 // 256 threads, one element each
    float v = src[t];
    float ss = v * v;
    #pragma unroll
    for (int o = 32; o > 0; o >>= 1) ss += __shfl_down(ss, o, 64);
    __shared__ float red[4];
    int lane = t & 63, w = t >> 6;
    if (lane == 0) red[w] = ss;
    __syncthreads();
    float tot = red[0] + red[1] + red[2] + red[3];
    float inv = rsqrtf(fmaxf(tot, 1e-16f));
    H[(size_t)row * D + t] = f2bf(v * inv);
}

// ------------------------------------------------------------- bf16 MFMA GEMM, dbuf pipeline
// C = F F^T. 128x128 tile, 4 waves of 64x64. BK=32, double-buffered LDS
// (2x8KB per matrix = 32 KB): STAGE(ks+1) issued before ds_read+MFMA of ks
// so global->LDS latency hides under compute; one barrier per step.
// LDS swizzle: 16B slot ^= (row>>1)&3  -> 2-way (free) bank access.
// Epilogue: direct-from-reg nontemporal stores (64B segments) + fused
// exp-rowsum partials.
__global__ __launch_bounds__(256, 3)
void gemm_bf16(const unsigned short* __restrict__ H,
               float* __restrict__ C,
               float* __restrict__ partials) {
    const int bc = blockIdx.x, br = blockIdx.y;

    __shared__ __align__(16) unsigned short As[2][BM * BK];   // 2 x 8 KB
    __shared__ __align__(16) unsigned short Bs[2][BM * BK];   // 2 x 8 KB

    const int t    = threadIdx.x;
    const int lane = t & 63;
    const int w    = t >> 6;      // wave id 0..3
    const int wm   = w >> 1;      // 0..1
    const int wn   = w & 1;       // 0..1

    f32x4 acc[4][4] = {};

    const unsigned short* Ab = H + (size_t)(br * BM) * D;
    const unsigned short* Bb = H + (size_t)(bc * BM) * D;

    // stage one BK-step into buffer `buf`; linear LDS dest (lane*16B),
    // inverse-swizzled global source (slot involution)
    #define STAGE(ks, buf)                                                     \
        {                                                                      \
            const int kk_ = (ks) * BK;                                         \
            _Pragma("unroll")                                                  \
            for (int i_ = 0; i_ < 2; ++i_) {                                   \
                int ch_   = w * 2 + i_;                /* 0..7, 1KB chunks */  \
                int row_  = ch_ * 16 + (lane >> 2);    /* 0..127 */            \
                int sl_   = (lane & 3) ^ ((row_ >> 1) & 3);                    \
                gload16(Ab + (size_t)row_ * D + kk_ + sl_ * 8,                 \
                        (unsigned short*)As[buf] + ch_ * 512);                 \
                gload16(Bb + (size_t)row_ * D + kk_ + sl_ * 8,                 \
                        (unsigned short*)Bs[buf] + ch_ * 512);                 \
            }                                                                  \
        }

    STAGE(0, 0);
    __syncthreads();

    for (int ks = 0; ks < KSTEPS; ++ks) {
        const int buf = ks & 1;
        if (ks < KSTEPS - 1) STAGE(ks + 1, buf ^ 1);   // prefetch next step

        bf16x8 a[4], b[4];
        #pragma unroll
        for (int m = 0; m < 4; ++m) {
            int row = wm * 64 + m * 16 + (lane & 15);
            int sl  = (lane >> 4) ^ ((row >> 1) & 3);
            a[m] = *(const bf16x8*)&As[buf][row * BK + sl * 8];
        }
        #pragma unroll
        for (int n = 0; n < 4; ++n) {
            int row = wn * 64 + n * 16 + (lane & 15);
            int sl  = (lane >> 4) ^ ((row >> 1) & 3);
            b[n] = *(const bf16x8*)&Bs[buf][row * BK + sl * 8];
        }
        __builtin_amdgcn_s_setprio(1);
        #pragma unroll
        for (int m = 0; m < 4; ++m)
            #pragma unroll
            for (int n = 0; n < 4; ++n)
                acc[m][n] = __builtin_amdgcn_mfma_f32_16x16x32_bf16(
                    a[m], b[n], acc[m][n], 0, 0, 0);
        __builtin_amdgcn_s_setprio(0);
        __syncthreads();
    }

    // ---- epilogue: NT store C + per-row exp sums (round-2 verified layout)
    const int gr0 = br * BM, gc0 = bc * BM;
    float rs[4][4];
    #pragma unroll
    for (int m = 0; m < 4; ++m)
        #pragma unroll
        for (int j = 0; j < 4; ++j) rs[m][j] = 0.0f;

    #pragma unroll
    for (int m = 0; m < 4; ++m) {
        #pragma unroll
        for (int n = 0; n < 4; ++n) {
            #pragma unroll
            for (int j = 0; j < 4; ++j) {
                int rl = wm * 64 + m * 16 + (lane >> 4) * 4 + j;
                int cl = wn * 64 + n * 16 + (lane & 15);
                float v = acc[m][n][j];
                __builtin_nontemporal_store(
                    v, &C[(size_t)(gr0 + rl) * NTOT + gc0 + cl]);
                float e = __expf(v * INV_TAU);
                if (gr0 + rl == gc0 + cl) e = 0.0f;   // mask diagonal
                rs[m][j] += e;
            }
        }
    }
    // reduce across the 16 lanes sharing a row (lane bits 0..3)
    #pragma unroll
    for (int m = 0; m < 4; ++m)
        #pragma unroll
        for (int j = 0; j < 4; ++j) {
            float s = rs[m][j];
            s += __shfl_xor(s, 1, 64);
            s += __shfl_xor(s, 2, 64);
            s += __shfl_xor(s, 4, 64);
            s += __shfl_xor(s, 8, 64);
            rs[m][j] = s;
        }
    // rowsum aliased onto dead staging LDS (all frag reads done at last barrier)
    float (*rowsum)[2] = (float(*)[2])&As[0][0];   // [128][2] = 1 KB
    if ((lane & 15) == 0) {
        #pragma unroll
        for (int m = 0; m < 4; ++m)
            #pragma unroll
            for (int j = 0; j < 4; ++j)
                rowsum[wm * 64 + m * 16 + (lane >> 4) * 4 + j][wn] = rs[m][j];
    }
    __syncthreads();
    if (t < BM)
        partials[(size_t)bc * NTOT + gr0 + t] = rowsum[t][0] + rowsum[t][1];
    #undef STAGE
}

// ------------------------------------------------------------- combine per-row
__global__ void loss_combine(const float* __restrict__ C,
                             const float* __restrict__ partials,
                             float* __restrict__ blocksum) {
    int r = blockIdx.x * 256 + threadIdx.x;   // 24 blocks x 256
    float s = 0.0f;
    #pragma unroll 8
    for (int b = 0; b < NBLK; ++b) s += partials[(size_t)b * NTOT + r];

    int k = r >> 11;          // r / 2048
    int i = r & 2047;
    float ps = 0.0f;
    #pragma unroll
    for (int j = 0; j < NMOD; ++j)
        if (j != k) ps += __expf(INV_TAU * C[(size_t)r * NTOT + i + j * N_TOK]);

    float rl = __logf(s) - __logf(ps);

    #pragma unroll
    for (int o = 32; o > 0; o >>= 1) rl += __shfl_down(rl, o, 64);
    __shared__ float red[4];
    int lane = threadIdx.x & 63, w = threadIdx.x >> 6;
    if (lane == 0) red[w] = rl;
    __syncthreads();
    if (threadIdx.x == 0)
        blocksum[blockIdx.x] = red[0] + red[1] + red[2] + red[3];
}

__global__ void final_sum(const float* __restrict__ blocksum, float* __restrict__ out) {
    int t = threadIdx.x;   // 64 threads
    float s = (t < 24) ? blocksum[t] : 0.0f;
    #pragma unroll
    for (int o = 32; o > 0; o >>= 1) s += __shfl_down(s, o, 64);
    if (t == 0) out[0] = s / (float)NTOT;
}

// ------------------------------------------------------------- launch
extern "C" void kernel_launch(void* const* d_in, const int* in_sizes, int n_in,
                              void* d_out, int out_size, void* d_ws, size_t ws_size,
                              hipStream_t stream) {
    const float* aerial = (const float*)d_in[0];
    const float* s2     = (const float*)d_in[1];
    const float* s1     = (const float*)d_in[2];
    float* out = (float*)d_out;

    unsigned short* H   = (unsigned short*)d_ws;                 // 6144*256 bf16 = 3 MB
    float* partials     = (float*)((char*)d_ws + (size_t)NTOT * D * 2);  // [48][6144] f32
    float* blocksum     = partials + (size_t)NBLK * NTOT;        // 24 floats
    float* C            = out + 1;                               // logits 6144x6144

    norm_kernel<<<NTOT, 256, 0, stream>>>(aerial, s2, s1, H);

    dim3 grid(NBLK, NBLK);
    gemm_bf16<<<grid, 256, 0, stream>>>(H, C, partials);

    loss_combine<<<NTOT / 256, 256, 0, stream>>>(C, partials, blocksum);
    final_sum<<<1, 64, 0, stream>>>(blocksum, out);
}

// Round 10
// 64.085 us; speedup vs baseline: 2.2738x; 2.2738x over previous
//
#include <hip/hip_runtime.h>
#include <math.h>

#define N_TOK 2048          // tokens per modality (64*32)
#define NMOD  3
#define NTOT  6144          // N_TOK * NMOD
#define D     256
#define INV_TAU 10.0f
#define LOG2E_TAU 14.4269504089f   // INV_TAU * log2(e)

#define BM 128              // output tile (rows == cols)
#define BK 32               // k-step (32 bf16 = 64 B rows)
#define NBLK (NTOT / BM)    // 48
#define KSTEPS (D / BK)     // 8

typedef float  f32x4  __attribute__((ext_vector_type(4)));
typedef short  bf16x8 __attribute__((ext_vector_type(8)));

// ------------------------------------------------------------- helpers
__device__ __forceinline__ unsigned short f2bf(float x) {
    unsigned int u = __float_as_uint(x);
    unsigned int r = (u + 0x7fffu + ((u >> 16) & 1u)) >> 16;   // RNE
    return (unsigned short)r;
}

__device__ __forceinline__ void gload16(const void* g, void* s) {
    __builtin_amdgcn_global_load_lds(
        (const __attribute__((address_space(1))) void*)g,
        (__attribute__((address_space(3))) void*)s, 16, 0, 0);
}

// ------------------------------------------------------------- normalize + bf16
__global__ void norm_kernel(const float* __restrict__ a,
                            const float* __restrict__ b,
                            const float* __restrict__ c,
                            unsigned short* __restrict__ H) {
    int row = blockIdx.x;
    const float* src;
    if (row < N_TOK)            src = a + (size_t)row * D;
    else if (row < 2 * N_TOK)   src = b + (size_t)(row - N_TOK) * D;
    else                        src = c + (size_t)(row - 2 * N_TOK) * D;

    int t = threadIdx.x;                 // 256 threads, one element each
    float v = src[t];
    float ss = v * v;
    #pragma unroll
    for (int o = 32; o > 0; o >>= 1) ss += __shfl_down(ss, o, 64);
    __shared__ float red[4];
    int lane = t & 63, w = t >> 6;
    if (lane == 0) red[w] = ss;
    __syncthreads();
    float tot = red[0] + red[1] + red[2] + red[3];
    float inv = rsqrtf(fmaxf(tot, 1e-16f));
    H[(size_t)row * D + t] = f2bf(v * inv);
}

// ------------------------------------------------------------- bf16 MFMA GEMM
// C = F F^T. 128x128 tile, 4 waves of 64x64. BK=32 double-buffered LDS
// (32 KB). Race-free bottom-sync pipeline: STAGE(ks+1 -> other buffer)
// issued at iteration top, current buffer computed, __syncthreads at
// bottom (implicit vmcnt(0) drains loads that aged a full compute phase;
// barrier separates writers of a buffer from its readers).
__global__ __launch_bounds__(256)
void gemm_bf16(const unsigned short* __restrict__ H,
               float* __restrict__ C,
               float* __restrict__ partials) {
    const int bc = blockIdx.x, br = blockIdx.y;

    __shared__ __align__(16) unsigned short As[2][BM * BK];   // 2 x 8 KB
    __shared__ __align__(16) unsigned short Bs[2][BM * BK];   // 2 x 8 KB

    const int t    = threadIdx.x;
    const int lane = t & 63;
    const int w    = t >> 6;      // wave id 0..3
    const int wm   = w >> 1;      // 0..1
    const int wn   = w & 1;       // 0..1

    f32x4 acc[4][4] = {};

    const unsigned short* Ab = H + (size_t)(br * BM) * D;
    const unsigned short* Bb = H + (size_t)(bc * BM) * D;

    // stage one BK-step (8KB/matrix = 8 chunks of 1KB; 2 chunks/wave/matrix).
    // linear LDS dest (lane*16B), inverse-swizzled global source.
    #define STAGE(ks, buf)                                                     \
        {                                                                      \
            const int kk_ = (ks) * BK;                                         \
            _Pragma("unroll")                                                  \
            for (int i_ = 0; i_ < 2; ++i_) {                                   \
                int ch_  = w * 2 + i_;                 /* 0..7 */              \
                int row_ = ch_ * 16 + (lane >> 2);     /* 0..127 */            \
                int sl_  = (lane & 3) ^ ((row_ >> 1) & 3);                     \
                gload16(Ab + (size_t)row_ * D + kk_ + sl_ * 8,                 \
                        (unsigned short*)As[buf] + ch_ * 512);                 \
                gload16(Bb + (size_t)row_ * D + kk_ + sl_ * 8,                 \
                        (unsigned short*)Bs[buf] + ch_ * 512);                 \
            }                                                                  \
        }

    STAGE(0, 0);
    __syncthreads();                               // buf0 ready

    #pragma unroll
    for (int ks = 0; ks < KSTEPS; ++ks) {
        const int buf = ks & 1;
        if (ks < KSTEPS - 1) STAGE(ks + 1, buf ^ 1);   // prefetch (other buffer)

        bf16x8 a[4], b[4];
        #pragma unroll
        for (int m = 0; m < 4; ++m) {
            int row = wm * 64 + m * 16 + (lane & 15);
            int sl  = (lane >> 4) ^ ((row >> 1) & 3);
            a[m] = *(const bf16x8*)&As[buf][row * BK + sl * 8];
        }
        #pragma unroll
        for (int n = 0; n < 4; ++n) {
            int row = wn * 64 + n * 16 + (lane & 15);
            int sl  = (lane >> 4) ^ ((row >> 1) & 3);
            b[n] = *(const bf16x8*)&Bs[buf][row * BK + sl * 8];
        }
        __builtin_amdgcn_s_setprio(1);
        #pragma unroll
        for (int m = 0; m < 4; ++m)
            #pragma unroll
            for (int n = 0; n < 4; ++n)
                acc[m][n] = __builtin_amdgcn_mfma_f32_16x16x32_bf16(
                    a[m], b[n], acc[m][n], 0, 0, 0);
        __builtin_amdgcn_s_setprio(0);
        __syncthreads();   // aged vmcnt(0) drain + barrier: next iter may overwrite buf
    }

    // ---- epilogue: store C + per-row exp sums (round-2 verified layout)
    const int gr0 = br * BM, gc0 = bc * BM;
    float rs[4][4];
    #pragma unroll
    for (int m = 0; m < 4; ++m)
        #pragma unroll
        for (int j = 0; j < 4; ++j) rs[m][j] = 0.0f;

    #pragma unroll
    for (int m = 0; m < 4; ++m) {
        #pragma unroll
        for (int n = 0; n < 4; ++n) {
            #pragma unroll
            for (int j = 0; j < 4; ++j) {
                int rl = wm * 64 + m * 16 + (lane >> 4) * 4 + j;
                int cl = wn * 64 + n * 16 + (lane & 15);
                float v = acc[m][n][j];
                C[(size_t)(gr0 + rl) * NTOT + gc0 + cl] = v;
                float e = exp2f(v * LOG2E_TAU);
                if (gr0 + rl == gc0 + cl) e = 0.0f;   // mask diagonal
                rs[m][j] += e;
            }
        }
    }
    // reduce across the 16 lanes sharing a row (lane bits 0..3)
    #pragma unroll
    for (int m = 0; m < 4; ++m)
        #pragma unroll
        for (int j = 0; j < 4; ++j) {
            float s = rs[m][j];
            s += __shfl_xor(s, 1, 64);
            s += __shfl_xor(s, 2, 64);
            s += __shfl_xor(s, 4, 64);
            s += __shfl_xor(s, 8, 64);
            rs[m][j] = s;
        }
    // rowsum aliased onto dead staging LDS (all reads done at final barrier)
    float (*rowsum)[2] = (float(*)[2])&As[0][0];   // [128][2] = 1 KB
    if ((lane & 15) == 0) {
        #pragma unroll
        for (int m = 0; m < 4; ++m)
            #pragma unroll
            for (int j = 0; j < 4; ++j)
                rowsum[wm * 64 + m * 16 + (lane >> 4) * 4 + j][wn] = rs[m][j];
    }
    __syncthreads();
    if (t < BM)
        partials[(size_t)bc * NTOT + gr0 + t] = rowsum[t][0] + rowsum[t][1];
    #undef STAGE
}

// ------------------------------------------------------------- combine per-row
__global__ void loss_combine(const float* __restrict__ C,
                             const float* __restrict__ partials,
                             float* __restrict__ blocksum) {
    int r = blockIdx.x * 256 + threadIdx.x;   // 24 blocks x 256
    float s = 0.0f;
    #pragma unroll 8
    for (int b = 0; b < NBLK; ++b) s += partials[(size_t)b * NTOT + r];

    int k = r >> 11;          // r / 2048
    int i = r & 2047;
    float ps = 0.0f;
    #pragma unroll
    for (int j = 0; j < NMOD; ++j)
        if (j != k) ps += __expf(INV_TAU * C[(size_t)r * NTOT + i + j * N_TOK]);

    float rl = __logf(s) - __logf(ps);

    #pragma unroll
    for (int o = 32; o > 0; o >>= 1) rl += __shfl_down(rl, o, 64);
    __shared__ float red[4];
    int lane = threadIdx.x & 63, w = threadIdx.x >> 6;
    if (lane == 0) red[w] = rl;
    __syncthreads();
    if (threadIdx.x == 0)
        blocksum[blockIdx.x] = red[0] + red[1] + red[2] + red[3];
}

__global__ void final_sum(const float* __restrict__ blocksum, float* __restrict__ out) {
    int t = threadIdx.x;   // 64 threads
    float s = (t < 24) ? blocksum[t] : 0.0f;
    #pragma unroll
    for (int o = 32; o > 0; o >>= 1) s += __shfl_down(s, o, 64);
    if (t == 0) out[0] = s / (float)NTOT;
}

// ------------------------------------------------------------- launch
extern "C" void kernel_launch(void* const* d_in, const int* in_sizes, int n_in,
                              void* d_out, int out_size, void* d_ws, size_t ws_size,
                              hipStream_t stream) {
    const float* aerial = (const float*)d_in[0];
    const float* s2     = (const float*)d_in[1];
    const float* s1     = (const float*)d_in[2];
    float* out = (float*)d_out;

    unsigned short* H   = (unsigned short*)d_ws;                 // 6144*256 bf16 = 3 MB
    float* partials     = (float*)((char*)d_ws + (size_t)NTOT * D * 2);  // [48][6144] f32
    float* blocksum     = partials + (size_t)NBLK * NTOT;        // 24 floats
    float* C            = out + 1;                               // logits 6144x6144

    norm_kernel<<<NTOT, 256, 0, stream>>>(aerial, s2, s1, H);

    dim3 grid(NBLK, NBLK);
    gemm_bf16<<<grid, 256, 0, stream>>>(H, C, partials);

    loss_combine<<<NTOT / 256, 256, 0, stream>>>(C, partials, blocksum);
    final_sum<<<1, 64, 0, stream>>>(blocksum, out);
}